// Round 3
// baseline (35.249 us; speedup 1.0000x reference)
//
#include <hip/hip_runtime.h>

// x: (B=2048, S=1024, D=12) f32. K = select_num = VOTE_PERHEAD = 24. S = 32*32.
constexpr int S_ = 1024;
constexpr int D_ = 12;
constexpr int K_ = 24;
constexpr int NT = 256;   // 4 waves; one block per batch row

__global__ __launch_bounds__(NT) void mhv_kernel(const float* __restrict__ x,
                                                 float* __restrict__ out_idx,  // B*K
                                                 float* __restrict__ out_cnt)  // B*S
{
    const int b    = blockIdx.x;
    const int tid  = threadIdx.x;
    const int lane = tid & 63;
    const int wid  = tid >> 6;

    __shared__ unsigned int       convp[S_ / 4];   // packed 4x u8 counts (max 16/byte)
    __shared__ unsigned long long cand[4 * K_];    // per-wave top-24 score keys
    __shared__ int                ck[256];         // conv-nonzero keys (<= 216)
    __shared__ int                glist[4 * K_];   // per-part top keys (<= 96)
    __shared__ int                wl[K_];          // final 24 winners
    __shared__ int                nck, ng;

    convp[tid] = 0u;
    if (tid == 0) { nck = 0; ng = 0; }

    // ---- load 4 scores/thread; 42-bit composite key: value desc, index asc ----
    const float* xb = x + (size_t)b * (S_ * D_);
    unsigned long long k[4];
    #pragma unroll
    for (int i = 0; i < 4; ++i) {
        int s = wid * 256 + i * 64 + lane;
        unsigned int su = 0u;                       // s==1023: no score, key = 0 (min)
        if (s < S_ - 1) {
            unsigned int bits = __float_as_uint(xb[(s + 1) * D_]);
            su = (bits & 0x80000000u) ? ~bits : (bits | 0x80000000u);  // monotone
        }
        k[i] = ((unsigned long long)su << 10) | (unsigned)(S_ - 1 - s);
    }

    // ---- per-wave exact 24th-largest via MSB->LSB binary search (ballot counts) ----
    unsigned long long t = 0ull;
    for (int bit = 41; bit >= 0; --bit) {
        unsigned long long tr = t | (1ull << bit);
        int c = __popcll(__ballot(k[0] >= tr)) + __popcll(__ballot(k[1] >= tr))
              + __popcll(__ballot(k[2] >= tr)) + __popcll(__ballot(k[3] >= tr));
        if (c >= K_) t = tr;
    }
    // exactly 24 keys >= t per wave (keys unique); compact to LDS
    {
        int base = wid * K_;
        #pragma unroll
        for (int i = 0; i < 4; ++i) {
            bool sel = (k[i] >= t);
            unsigned long long m = __ballot(sel);
            if (sel) cand[base + __popcll(m & ((1ull << lane) - 1ull))] = k[i];
            base += __popcll(m);
        }
    }
    __syncthreads();

    // ---- wave 0: global top-24 of the 96-key union; stamp 3x3 conv weights ----
    if (wid == 0) {
        unsigned long long g0 = cand[lane];
        unsigned long long g1 = (lane < 32) ? cand[64 + lane] : 0ull;
        unsigned long long t2 = 0ull;
        for (int bit = 41; bit >= 0; --bit) {
            unsigned long long tr = t2 | (1ull << bit);
            int c = __popcll(__ballot(g0 >= tr)) + __popcll(__ballot(g1 >= tr));
            if (c >= K_) t2 = tr;
        }
        #pragma unroll
        for (int i = 0; i < 2; ++i) {
            unsigned long long kk = (i == 0) ? g0 : g1;
            if (kk >= t2) {                          // one of exactly 24 winners
                int s = S_ - 1 - (int)(kk & 1023ull);
                int r = s >> 5, c0 = s & 31;
                #pragma unroll
                for (int dr = -1; dr <= 1; ++dr) {
                    int rr = r + dr;
                    if (rr < 0 || rr >= 32) continue;
                    #pragma unroll
                    for (int dc = -1; dc <= 1; ++dc) {
                        int cc = c0 + dc;
                        if (cc < 0 || cc >= 32) continue;
                        unsigned int w = ((dr == 0) ? 2u : 1u) * ((dc == 0) ? 2u : 1u);
                        int p = rr * 32 + cc;
                        atomicAdd(&convp[p >> 2], w << ((p & 3) * 8));
                    }
                }
            }
        }
    }
    __syncthreads();

    // ---- unpack counts, write output 1, compact nonzero keys (count desc, idx asc) ----
    unsigned int pw = convp[tid];
    {
        float4 o;
        o.x = (float)(pw & 255u);
        o.y = (float)((pw >> 8) & 255u);
        o.z = (float)((pw >> 16) & 255u);
        o.w = (float)(pw >> 24);
        *(float4*)(out_cnt + (size_t)b * S_ + tid * 4) = o;
    }
    #pragma unroll
    for (int j = 0; j < 4; ++j) {
        unsigned int cv = (pw >> (j * 8)) & 255u;
        bool sel = (cv != 0u);
        unsigned long long m = __ballot(sel);
        int cnt = __popcll(m);
        int wbase = 0;
        if (lane == 0) wbase = atomicAdd(&nck, cnt);
        wbase = __shfl(wbase, 0);
        if (sel) {
            int p = tid * 4 + j;
            ck[wbase + __popcll(m & ((1ull << lane) - 1ull))] =
                (int)(cv * 1024u) + (S_ - 1 - p);
        }
    }
    __syncthreads();

    // ---- partitioned exact select: wave w takes its slice (1 key/lane) ----
    int n = nck;                       // 24 <= n <= 216
    int q = (n + 3) >> 2;              // slice size <= 54
    int lo = wid * q, hi = min(n, lo + q);
    int myk = (lo + lane < hi) ? ck[lo + lane] : -1;
    int kw = min(K_, hi - lo);
    if (kw > 0) {
        int t3 = 0;
        for (int bit = 16; bit >= 0; --bit) {
            int tr = t3 | (1 << bit);
            int c = __popcll(__ballot(myk >= tr));
            if (c >= kw) t3 = tr;
        }
        bool sel = (myk >= t3);
        unsigned long long m = __ballot(sel);
        int cnt = __popcll(m);
        int gbase = 0;
        if (lane == 0) gbase = atomicAdd(&ng, cnt);
        gbase = __shfl(gbase, 0);
        if (sel) glist[gbase + __popcll(m & ((1ull << lane) - 1ull))] = myk;
    }
    __syncthreads();

    // ---- wave 0: top-24 of union (<= 96), rank, write output 0 ----
    if (wid == 0) {
        int n2 = ng;                   // 24 <= n2 <= 96
        int g0 = (lane < n2) ? glist[lane] : -1;
        int g1 = (64 + lane < n2) ? glist[64 + lane] : -1;
        int t4 = 0;
        for (int bit = 16; bit >= 0; --bit) {
            int tr = t4 | (1 << bit);
            int c = __popcll(__ballot(g0 >= tr)) + __popcll(__ballot(g1 >= tr));
            if (c >= K_) t4 = tr;
        }
        // compact exactly 24 winners
        {
            int base = 0;
            #pragma unroll
            for (int i = 0; i < 2; ++i) {
                int kk = (i == 0) ? g0 : g1;
                bool sel = (kk >= t4);
                unsigned long long m = __ballot(sel);
                if (sel) wl[base + __popcll(m & ((1ull << lane) - 1ull))] = kk;
                base += __popcll(m);
            }
        }
        if (lane < K_) {
            int kk = wl[lane];
            int rk = 0;
            #pragma unroll
            for (int j = 0; j < K_; ++j) rk += (wl[j] > kk);
            out_idx[(size_t)b * K_ + rk] = (float)(S_ - (kk & 1023));  // p + 1
        }
    }
}

extern "C" void kernel_launch(void* const* d_in, const int* in_sizes, int n_in,
                              void* d_out, int out_size, void* d_ws, size_t ws_size,
                              hipStream_t stream) {
    const float* x = (const float*)d_in[0];
    const int B = in_sizes[0] / (S_ * D_);

    float* out     = (float*)d_out;
    float* out_idx = out;                    // B*K_ (patch_idx, 1-based, as f32)
    float* out_cnt = out + (size_t)B * K_;   // B*S_ (count)

    mhv_kernel<<<dim3(B), dim3(NT), 0, stream>>>(x, out_idx, out_cnt);
}

// Round 4
// 25.201 us; speedup vs baseline: 1.3987x; 1.3987x over previous
//
#include <hip/hip_runtime.h>

// x: (B=2048, S=1024, D=12) f32. K = select_num = VOTE_PERHEAD = 24. S = 32*32.
constexpr int S_ = 1024;
constexpr int D_ = 12;
constexpr int K_ = 24;
constexpr int NT = 256;   // 4 waves; one block per batch row
constexpr int NL = 5;     // threshold-ladder rungs

// monotone-transformed (bits|0x80000000 for positive floats) ladder:
// {2.6f, 2.2f, 1.9f, 1.6f, 1.3f}
__constant__ const unsigned int U_LADDER[NL] =
    {0xC0266666u, 0xC00CCCCDu, 0xBFF33333u, 0xBFCCCCCDu, 0xBFA66666u};

__device__ __forceinline__ void stamp3x3(int p, unsigned int* convp) {
    int r = p >> 5, c0 = p & 31;
    #pragma unroll
    for (int dr = -1; dr <= 1; ++dr) {
        int rr = r + dr;
        if (rr < 0 || rr >= 32) continue;
        #pragma unroll
        for (int dc = -1; dc <= 1; ++dc) {
            int cc = c0 + dc;
            if (cc < 0 || cc >= 32) continue;
            unsigned int w = ((dr == 0) ? 2u : 1u) * ((dc == 0) ? 2u : 1u);
            int q = rr * 32 + cc;
            atomicAdd(&convp[q >> 2], w << ((q & 3) * 8));  // packed u8, max 16: no carry
        }
    }
}

__global__ __launch_bounds__(NT) void mhv_kernel(const float* __restrict__ x,
                                                 float* __restrict__ out_idx,  // B*K
                                                 float* __restrict__ out_cnt)  // B*S
{
    const int b    = blockIdx.x;
    const int tid  = threadIdx.x;
    const int lane = tid & 63;
    const int wid  = tid >> 6;

    __shared__ unsigned long long slab[S_];     // score candidate keys (worst case all)
    __shared__ unsigned int       convp[S_/4];  // packed 4x u8 conv counts
    __shared__ int                ck[96];       // count-candidates (count>=4): 24..96
    __shared__ int                wcnt[4][NL];  // per-wave ladder counts
    __shared__ int                ncand, nck;

    convp[tid] = 0u;
    if (tid == 0) { ncand = 0; nck = 0; }

    // ---- load 4 scores/thread, monotone key transform ----
    const float* xb = x + (size_t)b * (S_ * D_);
    unsigned int su[4];
    #pragma unroll
    for (int i = 0; i < 4; ++i) {
        int s = wid * 256 + i * 64 + lane;
        su[i] = 0u;                                // s==1023: no score (min key)
        if (s < S_ - 1) {
            unsigned int bits = __float_as_uint(xb[(s + 1) * D_]);
            su[i] = (bits & 0x80000000u) ? ~bits : (bits | 0x80000000u);
        }
    }

    // ---- ladder counts: 4 ballots per rung, lane0 posts wave totals ----
    int cw[NL];
    #pragma unroll
    for (int j = 0; j < NL; ++j) {
        int c = 0;
        #pragma unroll
        for (int i = 0; i < 4; ++i) c += __popcll(__ballot(su[i] >= U_LADDER[j]));
        cw[j] = c;
    }
    if (lane == 0) {
        #pragma unroll
        for (int j = 0; j < NL; ++j) wcnt[wid][j] = cw[j];
    }
    __syncthreads();

    // ---- choose tightest rung with block count >= K (fallback: all scores) ----
    int jsel = -1;
    #pragma unroll
    for (int j = 0; j < NL; ++j) {
        int ct = wcnt[0][j] + wcnt[1][j] + wcnt[2][j] + wcnt[3][j];
        if (jsel < 0 && ct >= K_) jsel = j;
    }
    unsigned int Usel = (jsel >= 0) ? U_LADDER[jsel] : 1u;   // su>=1 <=> real score

    // ---- compact candidate keys to LDS ----
    #pragma unroll
    for (int i = 0; i < 4; ++i) {
        bool sel = (su[i] >= Usel);
        unsigned long long m = __ballot(sel);
        int cnt = __popcll(m);
        int base = 0;
        if (lane == 0) base = atomicAdd(&ncand, cnt);
        base = __shfl(base, 0);
        if (sel) {
            int s = wid * 256 + i * 64 + lane;
            slab[base + __popcll(m & ((1ull << lane) - 1ull))] =
                ((unsigned long long)su[i] << 10) | (unsigned)(S_ - 1 - s);
        }
    }
    __syncthreads();

    // ---- exact rank among candidates; rank<24 stamps its 3x3 votes ----
    int c = ncand;                      // 24 <= c <= 1023, typically ~30
    if (c <= NT) {
        if (tid < c) {
            unsigned long long kk = slab[tid];
            int rk = 0;
            for (int j = 0; j < c; ++j) rk += (slab[j] > kk);
            if (rk < K_) stamp3x3(S_ - 1 - (int)(kk & 1023ull), convp);
        }
    } else {                            // cold fallback path, still exact
        unsigned long long kk0 = (tid          < c) ? slab[tid]          : 0ull;
        unsigned long long kk1 = (tid + NT     < c) ? slab[tid + NT]     : 0ull;
        unsigned long long kk2 = (tid + 2*NT   < c) ? slab[tid + 2*NT]   : 0ull;
        unsigned long long kk3 = (tid + 3*NT   < c) ? slab[tid + 3*NT]   : 0ull;
        int r0 = 0, r1 = 0, r2 = 0, r3 = 0;
        for (int j = 0; j < c; ++j) {
            unsigned long long kj = slab[j];
            r0 += (kj > kk0); r1 += (kj > kk1); r2 += (kj > kk2); r3 += (kj > kk3);
        }
        if (tid          < c && r0 < K_) stamp3x3(S_ - 1 - (int)(kk0 & 1023ull), convp);
        if (tid + NT     < c && r1 < K_) stamp3x3(S_ - 1 - (int)(kk1 & 1023ull), convp);
        if (tid + 2*NT   < c && r2 < K_) stamp3x3(S_ - 1 - (int)(kk2 & 1023ull), convp);
        if (tid + 3*NT   < c && r3 < K_) stamp3x3(S_ - 1 - (int)(kk3 & 1023ull), convp);
    }
    __syncthreads();

    // ---- unpack counts, write output 1, compact cells with count>=4 ----
    // Every vote center has count>=4 => 24 <= c2 <= 384/4 = 96, and the
    // top-24-by-(count,idx) is a subset of {count>=4}. No search needed.
    unsigned int pw = convp[tid];
    {
        float4 o;
        o.x = (float)(pw & 255u);
        o.y = (float)((pw >> 8) & 255u);
        o.z = (float)((pw >> 16) & 255u);
        o.w = (float)(pw >> 24);
        *(float4*)(out_cnt + (size_t)b * S_ + tid * 4) = o;
    }
    #pragma unroll
    for (int jj = 0; jj < 4; ++jj) {
        unsigned int cv = (pw >> (jj * 8)) & 255u;
        bool sel = (cv >= 4u);
        unsigned long long m = __ballot(sel);
        int cnt = __popcll(m);
        int base = 0;
        if (lane == 0) base = atomicAdd(&nck, cnt);
        base = __shfl(base, 0);
        if (sel) {
            int p = tid * 4 + jj;
            ck[base + __popcll(m & ((1ull << lane) - 1ull))] =
                (int)(cv << 10) | (S_ - 1 - p);        // count desc, index asc
        }
    }
    __syncthreads();

    // ---- exact stable rank; ranks 0..23 write output 0 ----
    int c2 = nck;                       // 24 <= c2 <= 96
    if (tid < c2) {
        int kk = ck[tid];
        int rk = 0;
        for (int j = 0; j < c2; ++j) rk += (ck[j] > kk);
        if (rk < K_) out_idx[(size_t)b * K_ + rk] = (float)(S_ - (kk & 1023)); // p+1
    }
}

extern "C" void kernel_launch(void* const* d_in, const int* in_sizes, int n_in,
                              void* d_out, int out_size, void* d_ws, size_t ws_size,
                              hipStream_t stream) {
    const float* x = (const float*)d_in[0];
    const int B = in_sizes[0] / (S_ * D_);

    float* out     = (float*)d_out;
    float* out_idx = out;                    // B*K_ (patch_idx, 1-based, as f32)
    float* out_cnt = out + (size_t)B * K_;   // B*S_ (count)

    mhv_kernel<<<dim3(B), dim3(NT), 0, stream>>>(x, out_idx, out_cnt);
}